// Round 6
// baseline (219.503 us; speedup 1.0000x reference)
//
#include <hip/hip_runtime.h>
#include <hip/hip_bf16.h>
#include <math.h>

#define NUM_HEADS 16
#define D_KV 64
#define D_MODEL 1024
#define SEQ 2048
#define BATCH 2
#define LOG2E 1.4426950408889634f

using bf16x8 = __attribute__((ext_vector_type(8))) short;
using bf16x4 = __attribute__((ext_vector_type(4))) short;
using f32x4  = __attribute__((ext_vector_type(4))) float;

__device__ inline unsigned short f2bf(float f) {
  union { float f; unsigned int i; } v; v.f = f;
  unsigned int u = v.i;
  return (unsigned short)((u + 0x7FFFu + ((u >> 16) & 1u)) >> 16);
}
__device__ inline unsigned short f2bf_fast(float f) {
  union { float f; unsigned int i; } v; v.f = f;
  return (unsigned short)((v.i + 0x8000u) >> 16);
}

#if __has_builtin(__builtin_amdgcn_exp2f)
#define EXP2(x) __builtin_amdgcn_exp2f(x)
#else
#define EXP2(x) __expf((x) * 0.6931471805599453f)
#endif

__device__ inline unsigned int pk_bf16(float a, float b) {
#if __has_builtin(__builtin_amdgcn_cvt_pk_bf16_f32)
  auto v = __builtin_amdgcn_cvt_pk_bf16_f32(a, b);
  unsigned int u; __builtin_memcpy(&u, &v, 4);
  return u;
#else
  return ((unsigned int)f2bf_fast(b) << 16) | f2bf_fast(a);
#endif
}

// async global->LDS, 16 B per lane (dest lane-contiguous)
__device__ inline void gld_lds16(const unsigned short* g, unsigned short* l) {
  __builtin_amdgcn_global_load_lds(
      (const __attribute__((address_space(1))) unsigned int*)g,
      (__attribute__((address_space(3))) unsigned int*)l, 16, 0, 0);
}

// ---------------- fused prep: X convert + 4 weight transposes + bias table ----------------
__global__ __launch_bounds__(256) void prep_kernel(const float* __restrict__ X,
                                                   const float* __restrict__ W0,
                                                   const float* __restrict__ W1,
                                                   const float* __restrict__ W2,
                                                   const float* __restrict__ W3,
                                                   const float* __restrict__ tbl,
                                                   unsigned short* __restrict__ xbf,
                                                   unsigned short* __restrict__ wt,
                                                   float* __restrict__ biasF) {
  __shared__ __align__(16) unsigned short T[64][72];
  int bid = blockIdx.x;
  int t = threadIdx.x;
  if (bid < 2048) {
    int i = (bid * 256 + t) * 8;
    __align__(16) unsigned short tmp[8];
#pragma unroll
    for (int e = 0; e < 8; e++) tmp[e] = f2bf(X[i + e]);
    *(uint4*)&xbf[i] = *(uint4*)tmp;
  } else if (bid < 3072) {
    int rem = bid - 2048;
    int z = rem >> 8, tid = rem & 255;
    const float* in = (z == 0) ? W0 : (z == 1) ? W1 : (z == 2) ? W2 : W3;
    unsigned short* o = wt + (long)z * 1048576;
    int r0 = (tid & 15) * 64, c0 = (tid >> 4) * 64;
#pragma unroll
    for (int i = 0; i < 2; i++) {
      int c = t + 256 * i; int r = c >> 3, k8 = (c & 7) * 8;
      const float* src = &in[(long)(r0 + r) * 1024 + c0 + k8];
      __align__(16) unsigned short tmp[8];
#pragma unroll
      for (int e = 0; e < 8; e++) tmp[e] = f2bf(src[e]);
      *(uint4*)&T[r][k8] = *(uint4*)tmp;
    }
    __syncthreads();
#pragma unroll
    for (int i = 0; i < 2; i++) {
      int c = t + 256 * i; int r = c >> 3, k8 = (c & 7) * 8;
      __align__(16) unsigned short tmp[8];
#pragma unroll
      for (int e = 0; e < 8; e++) tmp[e] = T[k8 + e][r];
      *(uint4*)&o[(long)(c0 + r) * 1024 + r0 + k8] = *(uint4*)tmp;
    }
  } else {
#pragma unroll
    for (int ii = 0; ii < 16; ii++) {
      int idx = t + 256 * ii;
      if (idx >= 4095) break;
      int rel = idx - 2047;
      int bucket = (rel > 0) ? 16 : 0;
      int rp = rel < 0 ? -rel : rel;
      int add;
      if (rp < 8) add = rp;
      else {
        int rl = 8 + (int)(logf((float)rp * 0.125f) / logf(16.0f) * 8.0f);
        add = rl < 15 ? rl : 15;
      }
      bucket += add;
#pragma unroll
      for (int h = 0; h < 16; h++) biasF[h * 4096 + idx] = tbl[bucket * 16 + h] * LOG2E;
    }
  }
}

// ---------------- GEMM: C(MxN) = X(MxK) @ Wt(NxK)^T, K=1024 ----------------
// mode 0: bf16 epilogue; z=0 (Q, log2e-scaled) and z=1 (K) scatter to (B,H,S,D);
//         z=2 (V) writes TRANSPOSED to (B,H,D,S) (folds old transpose_b2b kernel).
// mode 1: fp32 row-major epilogue.
__global__ __launch_bounds__(256) void gemm_kernel(const unsigned short* __restrict__ X,
                                                   const unsigned short* __restrict__ Wt,
                                                   unsigned short* __restrict__ out_b,
                                                   unsigned short* __restrict__ out_vt,
                                                   float* __restrict__ out_f, int mode) {
  __shared__ __align__(16) unsigned short As[128 * 32];
  __shared__ __align__(16) unsigned short Bs[128 * 32];
  const int K = 1024;
  int m0 = blockIdx.x * 128;
  int n0 = blockIdx.y * 128;
  const unsigned short* W = Wt + (long)blockIdx.z * 1048576;
  unsigned short* outq = (mode == 0) ? out_b + (long)blockIdx.z * 4194304 : nullptr;
  float scale = (mode == 0 && blockIdx.z == 0) ? LOG2E : 1.0f;
  int t = threadIdx.x;
  int w = t >> 6, l = t & 63;
  int wr = (w >> 1) * 64, wc = (w & 1) * 64;
  int lr = l & 15, lq = l >> 4;
  f32x4 acc[4][4];
#pragma unroll
  for (int i = 0; i < 4; i++)
#pragma unroll
    for (int j = 0; j < 4; j++) acc[i][j] = (f32x4){0.f, 0.f, 0.f, 0.f};

  for (int k0 = 0; k0 < K; k0 += 32) {
#pragma unroll
    for (int i = 0; i < 2; i++) {
      int c = t + 256 * i;
      int r = c >> 2, kc = (c & 3) * 8;
      gld_lds16(&X[(long)(m0 + r) * K + k0 + kc], &As[c * 8]);
      gld_lds16(&W[(long)(n0 + r) * K + k0 + kc], &Bs[c * 8]);
    }
    __syncthreads();
    bf16x8 a[4], b[4];
#pragma unroll
    for (int mi = 0; mi < 4; mi++) a[mi] = *(const bf16x8*)&As[(wr + mi * 16 + lr) * 32 + lq * 8];
#pragma unroll
    for (int ni = 0; ni < 4; ni++) b[ni] = *(const bf16x8*)&Bs[(wc + ni * 16 + lr) * 32 + lq * 8];
#pragma unroll
    for (int mi = 0; mi < 4; mi++)
#pragma unroll
      for (int ni = 0; ni < 4; ni++)
        acc[mi][ni] = __builtin_amdgcn_mfma_f32_16x16x32_bf16(a[mi], b[ni], acc[mi][ni], 0, 0, 0);
    __syncthreads();
  }

  if (mode == 0 && blockIdx.z == 2) {
    // V transposed: (B,H,D,S); per (mi,ni) the 4 regs are 4 consecutive s -> uint2
#pragma unroll
    for (int mi = 0; mi < 4; mi++)
#pragma unroll
      for (int ni = 0; ni < 4; ni++) {
        int n = n0 + wc + ni * 16 + lr;
        int h = n >> 6, d = n & 63;
        int mbase = m0 + wr + mi * 16 + lq * 4;
        int b2 = mbase >> 11, s = mbase & 2047;
        unsigned int s0 = ((unsigned int)f2bf(acc[mi][ni][1]) << 16) | f2bf(acc[mi][ni][0]);
        unsigned int s1 = ((unsigned int)f2bf(acc[mi][ni][3]) << 16) | f2bf(acc[mi][ni][2]);
        *(uint2*)&out_vt[(((long)(b2 * 16 + h) * 64 + d) << 11) + s] = (uint2){s0, s1};
      }
  } else {
#pragma unroll
    for (int mi = 0; mi < 4; mi++)
#pragma unroll
      for (int ni = 0; ni < 4; ni++)
#pragma unroll
        for (int r = 0; r < 4; r++) {
          int m = m0 + wr + mi * 16 + lq * 4 + r;
          int n = n0 + wc + ni * 16 + lr;
          float vf = acc[mi][ni][r] * scale;
          if (mode == 0) {
            int b2 = m >> 11, s = m & 2047, h = n >> 6, d = n & 63;
            outq[(((long)(b2 * NUM_HEADS + h) * SEQ) + s) * 64 + d] = f2bf(vf);
          } else {
            out_f[(long)m * 1024 + n] = vf;
          }
        }
  }
}

// ---------------- flash attention: 512-thread blocks, intra-block K-split ----------------
// 8 waves: group g = w>>2 handles even/odd 64-key tiles; each round stages 2 tiles with
// 2 barriers -> 1 barrier/tile, per-wave loop halves to 16 rounds, 16 waves/CU at 2 blk/CU.
// Transposed scores (S^T = K Q^T), no-max exp2 softmax, P in registers (16x16x16bf16_1k),
// row sums via ones-A MFMA. Partials merged via LDS overlay on the K/V buffers.
// NOTE: no min-wave launch bound — a 128-VGPR cap spills the ~150-VGPR loop (R4 lesson).
__global__ __launch_bounds__(512) void attn_kernel(const unsigned short* __restrict__ Q,
                                                   const unsigned short* __restrict__ Km,
                                                   const unsigned short* __restrict__ Vt,
                                                   const float* __restrict__ biasF,
                                                   unsigned short* __restrict__ O) {
  __shared__ __align__(16) unsigned short KV[4][4608];  // [0,1]=K par0/1, [2,3]=V par0/1 (64x72)
  __shared__ float biasS[2176];
  int q0 = blockIdx.x * 128;
  int bh = blockIdx.y;
  int b_ = bh >> 4, h = bh & 15;
  const unsigned short* Qb = Q  + (long)bh * SEQ * 64;
  const unsigned short* Kb = Km + (long)bh * SEQ * 64;
  const unsigned short* Vb = Vt + (long)bh * 64 * SEQ;
  const float* btabF = biasF + h * 4096;
  int t = threadIdx.x;
  int w = t >> 6, l = t & 63;
  int g = w >> 2, wg = w & 3;
  int lr = l & 15, lq = l >> 4;
  int qw = wg * 32;

  // single fp32 bias copy (log2e pre-scaled)
  int gbase = 1920 - q0;
  for (int i = t; i < 2176; i += 512) {
    int gi = gbase + i; if (gi > 4094) gi = 4094;
    biasS[i] = btabF[gi];
  }

  // Q fragments (B-operand for S^T), registers for whole kernel
  bf16x8 aq[2][2];
#pragma unroll
  for (int qt = 0; qt < 2; qt++)
#pragma unroll
    for (int ks = 0; ks < 2; ks++)
      aq[qt][ks] = *(const bf16x8*)&Qb[(long)(q0 + qw + qt * 16 + lr) * 64 + ks * 32 + lq * 8];

  // staging coords: 512 threads, 1 uint4 per (array, parity)
  int rs = t >> 3, fs = (t & 7) * 8;

  // prologue: tiles 0,1 -> LDS
  uint4 kpa = *(const uint4*)&Kb[(long)rs * 64 + fs];
  uint4 kpb = *(const uint4*)&Kb[(long)(64 + rs) * 64 + fs];
  uint4 vpa = *(const uint4*)&Vb[(long)rs * SEQ + fs];
  uint4 vpb = *(const uint4*)&Vb[(long)rs * SEQ + 64 + fs];
  *(uint4*)&KV[0][rs * 72 + fs] = kpa;
  *(uint4*)&KV[1][rs * 72 + fs] = kpb;
  *(uint4*)&KV[2][rs * 72 + fs] = vpa;
  *(uint4*)&KV[3][rs * 72 + fs] = vpb;

  f32x4 accO[4][2];   // [dt][qt], O^T C-tiles (row=d, col=q)
  f32x4 accL[2];
#pragma unroll
  for (int qt = 0; qt < 2; qt++) {
    accL[qt] = (f32x4){0.f, 0.f, 0.f, 0.f};
#pragma unroll
    for (int dt = 0; dt < 4; dt++) accO[dt][qt] = (f32x4){0.f, 0.f, 0.f, 0.f};
  }

  bf16x4 ones4;
#pragma unroll
  for (int e = 0; e < 4; e++) ones4[e] = (short)0x3F80;

  // bias index: global idx = vb - 16 + k0 + 16*m + r, m = kt-qt+1
  int vb = 127 + lq * 4 - qw - lr;
  int pbc = vb - 16;

  for (int i = 0; i < 16; i++) {
    __syncthreads();   // tiles 2i, 2i+1 visible
    int k0 = (2 * i + g) * 64;
    bool more = i < 15;

    // ---- bias values for this round (compiler merges to ds_read2_b32) ----
    float bbl[5][4];
    int pb = pbc + k0;
#pragma unroll
    for (int m = 0; m < 5; m++)
#pragma unroll
      for (int j = 0; j < 4; j++) bbl[m][j] = biasS[pb + 16 * m + j];

    // ---- K fragments (own parity buffer) ----
    bf16x8 bk[4][2];
#pragma unroll
    for (int kt = 0; kt < 4; kt++)
#pragma unroll
      for (int ks = 0; ks < 2; ks++)
        bk[kt][ks] = *(const bf16x8*)&KV[g][(kt * 16 + lr) * 72 + ks * 32 + lq * 8];

    // ---- prefetch next tile pair -> regs ----
    if (more) {
      const unsigned short* Kn = Kb + (long)(2 * i + 2) * 64 * 64;
      const unsigned short* Vn = Vb + (2 * i + 2) * 64;
      kpa = *(const uint4*)&Kn[(long)rs * 64 + fs];
      kpb = *(const uint4*)&Kn[(long)(64 + rs) * 64 + fs];
      vpa = *(const uint4*)&Vn[(long)rs * SEQ + fs];
      vpb = *(const uint4*)&Vn[(long)rs * SEQ + 64 + fs];
    }

    // ---- S^T = K Q^T ----
    f32x4 sacc[4][2];
#pragma unroll
    for (int kt = 0; kt < 4; kt++)
#pragma unroll
      for (int qt = 0; qt < 2; qt++) sacc[kt][qt] = (f32x4){0.f, 0.f, 0.f, 0.f};
#pragma unroll
    for (int ks = 0; ks < 2; ks++)
#pragma unroll
      for (int kt = 0; kt < 4; kt++)
#pragma unroll
        for (int qt = 0; qt < 2; qt++)
          sacc[kt][qt] = __builtin_amdgcn_mfma_f32_16x16x32_bf16(bk[kt][ks], aq[qt][ks], sacc[kt][qt], 0, 0, 0);

    // ---- p = exp2(s + bias'), pack to bf16 in regs (P^T C-layout) ----
    bf16x4 pk[4][2];
#pragma unroll
    for (int kt = 0; kt < 4; kt++)
#pragma unroll
      for (int qt = 0; qt < 2; qt++) {
        int blk = kt - qt + 1;
        float p0 = EXP2(sacc[kt][qt][0] + bbl[blk][0]);
        float p1 = EXP2(sacc[kt][qt][1] + bbl[blk][1]);
        float p2 = EXP2(sacc[kt][qt][2] + bbl[blk][2]);
        float p3 = EXP2(sacc[kt][qt][3] + bbl[blk][3]);
        unsigned int uu[2] = { pk_bf16(p0, p1), pk_bf16(p2, p3) };
        bf16x4 pv; __builtin_memcpy(&pv, uu, 8);
        pk[kt][qt] = pv;
      }

    // ---- O^T += V^T P^T ; row sums via ones ----
#pragma unroll
    for (int kt = 0; kt < 4; kt++) {
      bf16x4 va[4];
#pragma unroll
      for (int dt = 0; dt < 4; dt++)
        va[dt] = *(const bf16x4*)&KV[2 + g][(dt * 16 + lr) * 72 + kt * 16 + lq * 4];
#pragma unroll
      for (int qt = 0; qt < 2; qt++) {
#pragma unroll
        for (int dt = 0; dt < 4; dt++)
          accO[dt][qt] = __builtin_amdgcn_mfma_f32_16x16x16bf16_1k(va[dt], pk[kt][qt], accO[dt][qt], 0, 0, 0);
        accL[qt] = __builtin_amdgcn_mfma_f32_16x16x16bf16_1k(ones4, pk[kt][qt], accL[qt], 0, 0, 0);
      }
    }

    __syncthreads();   // all reads of current tiles done
    if (more) {
      *(uint4*)&KV[0][rs * 72 + fs] = kpa;
      *(uint4*)&KV[1][rs * 72 + fs] = kpb;
      *(uint4*)&KV[2][rs * 72 + fs] = vpa;
      *(uint4*)&KV[3][rs * 72 + fs] = vpb;
    }
  }

  // ---- merge group partials via LDS overlay on KV (34 floats/lane, stride-34 = 2-way max) ----
  float* mrg = (float*)&KV[0][0];
  int slot = (wg * 64 + l) * 34;
  if (g == 1) {
    float2* mp = (float2*)&mrg[slot];
    int j = 0;
#pragma unroll
    for (int dt = 0; dt < 4; dt++)
#pragma unroll
      for (int qt = 0; qt < 2; qt++) {
        mp[j++] = (float2){accO[dt][qt][0], accO[dt][qt][1]};
        mp[j++] = (float2){accO[dt][qt][2], accO[dt][qt][3]};
      }
    mp[16] = (float2){accL[0][0], accL[1][0]};
  }
  __syncthreads();
  if (g == 0) {
    const float2* mp = (const float2*)&mrg[slot];
    int j = 0;
#pragma unroll
    for (int dt = 0; dt < 4; dt++)
#pragma unroll
      for (int qt = 0; qt < 2; qt++) {
        float2 a = mp[j++], b2 = mp[j++];
        accO[dt][qt][0] += a.x;  accO[dt][qt][1] += a.y;
        accO[dt][qt][2] += b2.x; accO[dt][qt][3] += b2.y;
      }
    float2 ls = mp[16];
    float rl0 = 1.0f / (accL[0][0] + ls.x);
    float rl1 = 1.0f / (accL[1][0] + ls.y);
#pragma unroll
    for (int qt = 0; qt < 2; qt++) {
      float rl = qt ? rl1 : rl0;
      int q = q0 + qw + qt * 16 + lr;
#pragma unroll
      for (int dt = 0; dt < 4; dt++) {
        unsigned int s0 = ((unsigned int)f2bf(accO[dt][qt][1] * rl) << 16) | f2bf(accO[dt][qt][0] * rl);
        unsigned int s1 = ((unsigned int)f2bf(accO[dt][qt][3] * rl) << 16) | f2bf(accO[dt][qt][2] * rl);
        *(uint2*)&O[((long)(b_ * SEQ + q)) * 1024 + h * 64 + dt * 16 + lq * 4] = (uint2){s0, s1};
      }
    }
  }
}

extern "C" void kernel_launch(void* const* d_in, const int* in_sizes, int n_in,
                              void* d_out, int out_size, void* d_ws, size_t ws_size,
                              hipStream_t stream) {
  const float* X   = (const float*)d_in[0];
  const float* Wq  = (const float*)d_in[1];
  const float* Wk  = (const float*)d_in[2];
  const float* Wv  = (const float*)d_in[3];
  const float* Wo  = (const float*)d_in[4];
  const float* tbl = (const float*)d_in[5];

  unsigned short* wt    = (unsigned short*)d_ws;       // 4 x 1M elems (Wq,Wk,Wv,Wo transposed)
  unsigned short* xbf   = wt + 4 * 1048576;            // 4M elems
  unsigned short* q_ws  = xbf + 4194304;               // Q,K,V slots (V slot unused)
  unsigned short* k_ws  = q_ws + 4194304;
  unsigned short* v_ws  = k_ws + 4194304;
  unsigned short* vt_ws = v_ws + 4194304;              // V^T (B,H,64,S), written by gemm z=2
  unsigned short* o_ws  = vt_ws + 4194304;
  float* biasF = (float*)(o_ws + 4194304);             // 16 x 4096 fp32 (log2e-scaled)

  prep_kernel<<<3073, 256, 0, stream>>>(X, Wq, Wk, Wv, Wo, tbl, xbf, wt, biasF);
  gemm_kernel<<<dim3(32, 8, 3), 256, 0, stream>>>(xbf, wt, q_ws, vt_ws, nullptr, 0);
  attn_kernel<<<dim3(16, 32), 512, 0, stream>>>(q_ws, k_ws, vt_ws, biasF, o_ws);
  gemm_kernel<<<dim3(32, 8, 1), 256, 0, stream>>>(o_ws, wt + 3 * 1048576, nullptr, nullptr, (float*)d_out, 1);
}